// Round 3
// baseline (476.628 us; speedup 1.0000x reference)
//
#include <hip/hip_runtime.h>
#include <hip/hip_bf16.h>
#include <hip/hip_cooperative_groups.h>

namespace cg = cooperative_groups;

#define BB 4
#define NN 256           // nodes per batch
#define FD 128
#define HH 256
#define G3 384           // 3*F
#define STEPS 6
#define PO 896           // proj width: Ai[0:256) | Aj[256:512) | gh[512:896)
#define NODES (BB*NN)    // 1024

typedef __hip_bfloat16 bf16;

// ---- all scratch in device globals (d_ws untrusted) ----
__device__ float g_h[NODES*FD];
__device__ float g_proj[2*NODES*PO];    // double-buffered across steps
__device__ float g_av2[NODES*2*NN];     // [grp][j][r][2] : (adj, valid)
__device__ float g_deg[NODES];
__device__ float g_mask[NODES];
__device__ float g_PT[FD*PO];           // [f][out]: W1i^T | W1j^T | Whh^T
__device__ float g_pbias[PO];
__device__ float g_w1e[HH];
__device__ float g_WihT[HH*G3];         // [h2][g]
__device__ float g_MT[HH*G3];           // [k][g] = (Wih@W2)[g][k]
__device__ float g_bv[G3];
__device__ float g_bihf[G3];

__device__ __forceinline__ float b2f(bf16 v){ return __bfloat162float(v); }
__device__ __forceinline__ float ldin(const void* p, int i, int isb){
  return isb ? b2f(((const bf16*)p)[i]) : ((const float*)p)[i];
}
__device__ __forceinline__ int probe_bf16(const void* mask){
  return ((const unsigned short*)mask)[0] == 0x3F80 ? 1 : 0;  // bf16 1.0 halfword
}

// ================= init A: everything input-only =================
// blocks [0,1024): adj row per node | [1024,1472): PT | [1472,1728): WihT
// [1728,2240): h | 2240: small vectors
__global__ __launch_bounds__(256) void k_init_a(
    const void* __restrict__ x, const void* __restrict__ adj,
    const void* __restrict__ mask, const void* __restrict__ W1,
    const void* __restrict__ b1, const void* __restrict__ Wih,
    const void* __restrict__ Whh, const void* __restrict__ bhh){
  int isb = probe_bf16(mask);
  int blk = blockIdx.x, tid = threadIdx.x;
  if (blk < 1024){                       // adj/valid/deg/mask for node = blk
    int node = blk, b = node >> 8, j = tid;
    float mi = ldin(mask, node, isb);
    float mj = ldin(mask, b*NN + j, isb);
    float a  = ldin(adj, node*NN + j, isb);
    float valid = (a > 0.f && mj > 0.f && mi > 0.f) ? 1.f : 0.f;
    int grp = node >> 2, r = node & 3;
    g_av2[grp*2048 + j*8 + r*2]     = a;
    g_av2[grp*2048 + j*8 + r*2 + 1] = valid;
    __shared__ float red[4];
    float s = valid;
    #pragma unroll
    for (int o = 32; o > 0; o >>= 1) s += __shfl_down(s, o, 64);
    if ((j & 63) == 0) red[j >> 6] = s;
    __syncthreads();
    if (j == 0){ g_deg[node] = red[0]+red[1]+red[2]+red[3]; g_mask[node] = mi; }
    return;
  }
  if (blk < 1472){                       // PT
    int i = (blk - 1024)*256 + tid;      // < 114688
    int f = i / PO, o = i % PO;
    float v;
    if (o < 256)       v = ldin(W1, o*257 + f, isb);
    else if (o < 512)  v = ldin(W1, (o-256)*257 + FD + f, isb);
    else               v = ldin(Whh, (o-512)*FD + f, isb);
    g_PT[i] = v;
    return;
  }
  if (blk < 1728){                       // WihT[h2][g] = Wih[g][h2]
    int h2 = blk - 1472;
    for (int g = tid; g < G3; g += 256)
      g_WihT[h2*G3 + g] = ldin(Wih, g*HH + h2, isb);
    return;
  }
  if (blk < 2240){                       // h init
    int i = (blk - 1728)*256 + tid;      // < 131072
    g_h[i] = ldin(x, i, isb);
    return;
  }
  // small vectors
  for (int i = tid; i < PO; i += 256){
    float v = 0.f;
    if (i < 256) v = ldin(b1, i, isb);
    else if (i >= 512) v = ldin(bhh, i-512, isb);
    g_pbias[i] = v;
  }
  for (int i = tid; i < HH; i += 256) g_w1e[i] = ldin(W1, i*257 + 256, isb);
  for (int i = tid; i < G3; i += 256) g_bihf[i] = 0.f;  // placeholder; set in MT
}

// ================= init B: MT = (Wih@W2)^T, bv, bihf =================
__global__ __launch_bounds__(384) void k_init_MT(const void* __restrict__ W2,
                                                 const void* __restrict__ b2,
                                                 const void* __restrict__ bih,
                                                 const void* __restrict__ mask){
  int isb = probe_bf16(mask);
  int k = blockIdx.x;     // 0..256 (k==256 -> bv + bihf)
  int g = threadIdx.x;    // 0..383
  __shared__ float col[HH];          // W2[:,k] (or b2)
  if (g < HH){
    col[g] = (k < HH) ? ldin(W2, g*HH + k, isb) : ldin(b2, g, isb);
  }
  __syncthreads();
  const float* wp = g_WihT + g;      // coalesced across threads, stride G3 per h2
  float a0 = 0.f, a1 = 0.f, a2 = 0.f, a3 = 0.f;
  #pragma unroll 8
  for (int h2 = 0; h2 < HH; h2 += 4){
    a0 = fmaf(col[h2+0], wp[(h2+0)*G3], a0);
    a1 = fmaf(col[h2+1], wp[(h2+1)*G3], a1);
    a2 = fmaf(col[h2+2], wp[(h2+2)*G3], a2);
    a3 = fmaf(col[h2+3], wp[(h2+3)*G3], a3);
  }
  float acc = (a0 + a1) + (a2 + a3);
  if (k < HH){
    g_MT[k*G3 + g] = acc;
  } else {
    g_bv[g] = acc;
    g_bihf[g] = ldin(bih, g, isb);
  }
}

// ================= persistent step kernel (cooperative) =================
// All 7 step iterations in ONE dispatch; grid.sync() replaces launch
// boundaries (~2-3 us vs ~7-9 us each). Only cross-block dependency is
// proj-write -> next-step S-read, handled by double-buffered g_proj + the
// per-step grid.sync. Loop-invariant state hoisted: av2 tile lives in a
// dedicated LDS region loaded once; isb/w1e/bv/bihf/deg/mask/pbias in regs.
__global__ __launch_bounds__(512) void k_steps(void* __restrict__ out,
                                               const void* __restrict__ mask){
  cg::grid_group grid = cg::this_grid();
  int grp = blockIdx.x, tid = threadIdx.x, n0 = grp*4;
  __shared__ __align__(16) float Ssh[4][HH];   // 4 KB
  __shared__ __align__(16) float hsh[4][FD];   // 2 KB
  __shared__ __align__(16) float avs[NN*8];    // 8 KB, persistent adj/valid
  __shared__ __align__(16) char uni[47104];    // 46 KB phase overlay
  float2 (*red)[4][128]  = (float2 (*)[4][128])(uni + 8192);   // S phase
  float  (*part)[4][G3]  = (float  (*)[4][G3])uni;             // gi GEMM
  float  (*Aa)[G3]       = (float  (*)[G3])(uni + 24576);
  float  (*Bs)[FD]       = (float  (*)[FD])(uni + 30720);
  float4 (*ppart)[224]   = (float4 (*)[224])(uni + 32768);     // proj

  int isb = probe_bf16(mask);
  // --- S-phase roles (persistent) ---
  int hp = tid & 127;                  // h-pair: h = 2hp, 2hp+1
  int q  = tid >> 7;                   // j-quarter (wave-uniform)
  int bb = grp >> 6;
  float2 w12 = ((const float2*)g_w1e)[hp];
  // --- gi-GEMM roles ---
  int c96 = tid % 96, sub = tid / 96;
  float bvg = 0.f, bihg = 0.f;
  if (tid < G3){ bvg = g_bv[tid]; bihg = g_bihf[tid]; }
  float deg4[4], msk4[4];
  #pragma unroll
  for (int r = 0; r < 4; ++r){ deg4[r] = g_deg[n0+r]; msk4[r] = g_mask[n0+r]; }
  // --- proj roles ---
  int c = tid & 255, fh = tid >> 8;
  float4 pb = make_float4(0.f,0.f,0.f,0.f);
  if (c < 224) pb = ((const float4*)g_pbias)[c];
  // --- adj/valid tile: load once, persist across steps ---
  ((float4*)avs)[tid] = ((const float4*)(g_av2 + grp*2048))[tid];
  __syncthreads();

  for (int s = 0; s <= STEPS; ++s){
    const float* projr = g_proj + ((s+1)&1)*(NODES*PO);
    float*       projw = g_proj + (s&1)*(NODES*PO);
    int last = (s == STEPS);

    if (s){
      // ---------- S phase: S[i][h] = sum_j relu(Ai+Aj+adj*w1e)*valid ----------
      float2 Ai2[4], acc2[4];
      #pragma unroll
      for (int r = 0; r < 4; ++r){
        Ai2[r] = *(const float2*)(projr + (n0+r)*PO + 2*hp);
        acc2[r] = make_float2(0.f, 0.f);
      }
      const float* ajp = projr + (bb*NN + q*64)*PO + 256 + 2*hp;
      const float4* avp = ((const float4*)avs) + q*128;   // 2 float4 per j
      #pragma unroll 4
      for (int j = 0; j < 64; ++j){
        float2 a2 = *(const float2*)ajp; ajp += PO;
        float4 av01 = avp[2*j];
        float4 av23 = avp[2*j+1];
        float adv[4] = {av01.x, av01.z, av23.x, av23.z};
        float vmv[4] = {av01.y, av01.w, av23.y, av23.w};
        #pragma unroll
        for (int r = 0; r < 4; ++r){
          float vx = Ai2[r].x + a2.x;
          float vy = Ai2[r].y + a2.y;
          vx = fmaf(adv[r], w12.x, vx);
          vy = fmaf(adv[r], w12.y, vy);
          vx = fmaxf(vx, 0.f); vy = fmaxf(vy, 0.f);
          acc2[r].x = fmaf(vx, vmv[r], acc2[r].x);
          acc2[r].y = fmaf(vy, vmv[r], acc2[r].y);
        }
      }
      if (q){
        #pragma unroll
        for (int r = 0; r < 4; ++r) red[q-1][r][hp] = acc2[r];
      }
      __syncthreads();
      if (q == 0){
        #pragma unroll
        for (int r = 0; r < 4; ++r){
          float2 sv = acc2[r];
          float2 p0 = red[0][r][hp], p1 = red[1][r][hp], p2 = red[2][r][hp];
          sv.x += p0.x + p1.x + p2.x;
          sv.y += p0.y + p1.y + p2.y;
          ((float2*)&Ssh[r][0])[hp] = sv;
        }
      }
      __syncthreads();                  // S done; part may overwrite red region

      // ---------- gi GEMM: part = Ssh @ MT (K split 4 ways) ----------
      if (tid < 384){
        int k0 = sub*64;
        float4 acc[4];
        #pragma unroll
        for (int r = 0; r < 4; ++r) acc[r] = make_float4(0.f,0.f,0.f,0.f);
        const float4* MT4 = (const float4*)g_MT;   // [256][96]
        #pragma unroll 4
        for (int k = 0; k < 64; ++k){
          float4 m = MT4[(k0+k)*96 + c96];
          #pragma unroll
          for (int r = 0; r < 4; ++r){
            float sv = Ssh[r][k0+k];
            acc[r].x = fmaf(sv, m.x, acc[r].x);
            acc[r].y = fmaf(sv, m.y, acc[r].y);
            acc[r].z = fmaf(sv, m.z, acc[r].z);
            acc[r].w = fmaf(sv, m.w, acc[r].w);
          }
        }
        #pragma unroll
        for (int r = 0; r < 4; ++r) ((float4*)&part[sub][r][0])[c96] = acc[r];
      }
      __syncthreads();
      if (tid < 384){
        int g = tid;
        #pragma unroll
        for (int r = 0; r < 4; ++r){
          float gi = part[0][r][g] + part[1][r][g] + part[2][r][g] + part[3][r][g]
                   + deg4[r]*bvg + bihg;
          float gh = projr[(n0+r)*PO + 512 + g];
          if (g < 256) Aa[r][g] = gi + gh;
          else { Aa[r][g] = gi; Bs[r][g-256] = gh; }
        }
      }
      __syncthreads();
      // ---------- GRU ----------
      if (tid < 128){
        int f = tid;
        #pragma unroll
        for (int r = 0; r < 4; ++r){
          int node = n0 + r;
          float rr = 1.f/(1.f + __expf(-Aa[r][f]));
          float zz = 1.f/(1.f + __expf(-Aa[r][128+f]));
          float hn = Bs[r][f];
          float narg = Aa[r][256+f] + rr*hn;
          float e = __expf(2.f*narg);
          float nn = 1.f - 2.f/(e + 1.f);
          float hp_ = g_h[node*FD + f];
          float hv = (1.f - zz)*nn + zz*hp_;
          hv *= msk4[r];
          hsh[r][f] = hv;
          g_h[node*FD + f] = hv;
          if (last){
            if (isb) ((bf16*)out)[node*FD + f] = __float2bfloat16(hv);
            else     ((float*)out)[node*FD + f] = hv;
          }
        }
      }
      __syncthreads();
    } else {
      if (tid < 128) ((float4*)&hsh[0][0])[tid] = ((const float4*)(g_h + n0*FD))[tid];
      __syncthreads();
    }

    if (!last){                        // proj for this step's h -> write buffer
      float4 acc[4];
      #pragma unroll
      for (int r = 0; r < 4; ++r) acc[r] = make_float4(0.f,0.f,0.f,0.f);
      if (c < 224){
        const float4* PT4 = (const float4*)g_PT + fh*64*224 + c;
        #pragma unroll 4
        for (int f = 0; f < 64; ++f){
          float4 w = *PT4; PT4 += 224;
          #pragma unroll
          for (int r = 0; r < 4; ++r){
            float hv = hsh[r][fh*64 + f];
            acc[r].x = fmaf(hv, w.x, acc[r].x);
            acc[r].y = fmaf(hv, w.y, acc[r].y);
            acc[r].z = fmaf(hv, w.z, acc[r].z);
            acc[r].w = fmaf(hv, w.w, acc[r].w);
          }
        }
        if (fh == 1){
          #pragma unroll
          for (int r = 0; r < 4; ++r) ppart[r][c] = acc[r];
        }
      }
      __syncthreads();
      if (fh == 0 && c < 224){
        #pragma unroll
        for (int r = 0; r < 4; ++r){
          float4 p = ppart[r][c];
          float4 res;
          res.x = acc[r].x + p.x + pb.x;
          res.y = acc[r].y + p.y + pb.y;
          res.z = acc[r].z + p.z + pb.z;
          res.w = acc[r].w + p.w + pb.w;
          ((float4*)(projw + (n0+r)*PO))[c] = res;
        }
      }
      grid.sync();                     // proj visible to all blocks' next S
    }
  }
}

extern "C" void kernel_launch(void* const* d_in, const int* in_sizes, int n_in,
                              void* d_out, int out_size, void* d_ws, size_t ws_size,
                              hipStream_t stream){
  (void)in_sizes; (void)n_in; (void)out_size; (void)d_ws; (void)ws_size;
  const void* x    = d_in[0];
  const void* adj  = d_in[1];
  const void* mask = d_in[2];
  const void* W1   = d_in[3];
  const void* b1   = d_in[4];
  const void* W2   = d_in[5];
  const void* b2   = d_in[6];
  const void* Wih  = d_in[7];
  const void* bih  = d_in[8];
  const void* Whh  = d_in[9];
  const void* bhh  = d_in[10];

  k_init_a<<<2241, 256, 0, stream>>>(x, adj, mask, W1, b1, Wih, Whh, bhh);
  k_init_MT<<<HH + 1, 384, 0, stream>>>(W2, b2, bih, mask);

  void* outp = d_out;
  const void* maskp = mask;
  void* args[2] = { (void*)&outp, (void*)&maskp };
  hipLaunchCooperativeKernel((const void*)k_steps, dim3(NODES/4), dim3(512),
                             args, 0, stream);
}

// Round 4
// 379.071 us; speedup vs baseline: 1.2574x; 1.2574x over previous
//
#include <hip/hip_runtime.h>
#include <hip/hip_bf16.h>

#define BB 4
#define NN 256           // nodes per batch
#define FD 128
#define HH 256
#define G3 384           // 3*F
#define STEPS 6
#define PO 896           // proj width: Ai[0:256) | Aj[256:512) | gh[512:896)
#define NODES (BB*NN)    // 1024

typedef __hip_bfloat16 bf16;

// ---- all scratch in device globals (d_ws untrusted) ----
__device__ float g_h[NODES*FD];
__device__ float g_proj[2*NODES*PO];    // double-buffered across steps
__device__ float g_av2[NODES*2*NN];     // [grp][j][r][2] : (adj, valid)
__device__ float g_deg[NODES];
__device__ float g_mask[NODES];
__device__ float g_PT[FD*PO];           // [f][out]: W1i^T | W1j^T | Whh^T
__device__ float g_pbias[PO];
__device__ float g_w1e[HH];
__device__ float g_WihT[HH*G3];         // [h2][g]
__device__ float g_MT[HH*G3];           // [k][g] = (Wih@W2)[g][k]
__device__ float g_bv[G3];
__device__ float g_bihf[G3];
__device__ int   g_bar4[4];             // per-batch barrier counters (zeroed in k_init_a)

__device__ __forceinline__ float b2f(bf16 v){ return __bfloat162float(v); }
__device__ __forceinline__ float ldin(const void* p, int i, int isb){
  return isb ? b2f(((const bf16*)p)[i]) : ((const float*)p)[i];
}
__device__ __forceinline__ int probe_bf16(const void* mask){
  return ((const unsigned short*)mask)[0] == 0x3F80 ? 1 : 0;  // bf16 1.0 halfword
}

// ================= init A: everything input-only =================
// blocks [0,1024): adj row per node | [1024,1472): PT | [1472,1728): WihT
// [1728,2240): h | 2240: small vectors + barrier reset
__global__ __launch_bounds__(256) void k_init_a(
    const void* __restrict__ x, const void* __restrict__ adj,
    const void* __restrict__ mask, const void* __restrict__ W1,
    const void* __restrict__ b1, const void* __restrict__ Wih,
    const void* __restrict__ Whh, const void* __restrict__ bhh){
  int isb = probe_bf16(mask);
  int blk = blockIdx.x, tid = threadIdx.x;
  if (blk < 1024){                       // adj/valid/deg/mask for node = blk
    int node = blk, b = node >> 8, j = tid;
    float mi = ldin(mask, node, isb);
    float mj = ldin(mask, b*NN + j, isb);
    float a  = ldin(adj, node*NN + j, isb);
    float valid = (a > 0.f && mj > 0.f && mi > 0.f) ? 1.f : 0.f;
    int grp = node >> 2, r = node & 3;
    g_av2[grp*2048 + j*8 + r*2]     = a;
    g_av2[grp*2048 + j*8 + r*2 + 1] = valid;
    __shared__ float red[4];
    float s = valid;
    #pragma unroll
    for (int o = 32; o > 0; o >>= 1) s += __shfl_down(s, o, 64);
    if ((j & 63) == 0) red[j >> 6] = s;
    __syncthreads();
    if (j == 0){ g_deg[node] = red[0]+red[1]+red[2]+red[3]; g_mask[node] = mi; }
    return;
  }
  if (blk < 1472){                       // PT
    int i = (blk - 1024)*256 + tid;      // < 114688
    int f = i / PO, o = i % PO;
    float v;
    if (o < 256)       v = ldin(W1, o*257 + f, isb);
    else if (o < 512)  v = ldin(W1, (o-256)*257 + FD + f, isb);
    else               v = ldin(Whh, (o-512)*FD + f, isb);
    g_PT[i] = v;
    return;
  }
  if (blk < 1728){                       // WihT[h2][g] = Wih[g][h2]
    int h2 = blk - 1472;
    for (int g = tid; g < G3; g += 256)
      g_WihT[h2*G3 + g] = ldin(Wih, g*HH + h2, isb);
    return;
  }
  if (blk < 2240){                       // h init
    int i = (blk - 1728)*256 + tid;      // < 131072
    g_h[i] = ldin(x, i, isb);
    return;
  }
  // small vectors + barrier counter reset (runs before k_steps, stream-ordered)
  if (tid < 4) g_bar4[tid] = 0;
  for (int i = tid; i < PO; i += 256){
    float v = 0.f;
    if (i < 256) v = ldin(b1, i, isb);
    else if (i >= 512) v = ldin(bhh, i-512, isb);
    g_pbias[i] = v;
  }
  for (int i = tid; i < HH; i += 256) g_w1e[i] = ldin(W1, i*257 + 256, isb);
  for (int i = tid; i < G3; i += 256) g_bihf[i] = 0.f;  // placeholder; set in MT
}

// ================= init B: MT = (Wih@W2)^T, bv, bihf =================
__global__ __launch_bounds__(384) void k_init_MT(const void* __restrict__ W2,
                                                 const void* __restrict__ b2,
                                                 const void* __restrict__ bih,
                                                 const void* __restrict__ mask){
  int isb = probe_bf16(mask);
  int k = blockIdx.x;     // 0..256 (k==256 -> bv + bihf)
  int g = threadIdx.x;    // 0..383
  __shared__ float col[HH];          // W2[:,k] (or b2)
  if (g < HH){
    col[g] = (k < HH) ? ldin(W2, g*HH + k, isb) : ldin(b2, g, isb);
  }
  __syncthreads();
  const float* wp = g_WihT + g;      // coalesced across threads, stride G3 per h2
  float a0 = 0.f, a1 = 0.f, a2 = 0.f, a3 = 0.f;
  #pragma unroll 8
  for (int h2 = 0; h2 < HH; h2 += 4){
    a0 = fmaf(col[h2+0], wp[(h2+0)*G3], a0);
    a1 = fmaf(col[h2+1], wp[(h2+1)*G3], a1);
    a2 = fmaf(col[h2+2], wp[(h2+2)*G3], a2);
    a3 = fmaf(col[h2+3], wp[(h2+3)*G3], a3);
  }
  float acc = (a0 + a1) + (a2 + a3);
  if (k < HH){
    g_MT[k*G3 + g] = acc;
  } else {
    g_bv[g] = acc;
    g_bihf[g] = ldin(bih, g, isb);
  }
}

// ---- per-batch barrier: 64 blocks, agent-scope release/add -> spin -> acquire
// (Guideline-16 protocol; replaces grid.sync()'s ~35us with ~2-4us.)
__device__ __forceinline__ void batch_barrier(int bb, int tgt, int tid){
  __syncthreads();                       // drains vmcnt: all block stores at L2
  if (tid == 0){
    __builtin_amdgcn_fence(__ATOMIC_RELEASE, "agent");   // wb L2 -> coherent point
    __hip_atomic_fetch_add(&g_bar4[bb], 1, __ATOMIC_RELAXED,
                           __HIP_MEMORY_SCOPE_AGENT);
    while (__hip_atomic_load(&g_bar4[bb], __ATOMIC_RELAXED,
                             __HIP_MEMORY_SCOPE_AGENT) < tgt)
      __builtin_amdgcn_s_sleep(8);
    __builtin_amdgcn_fence(__ATOMIC_ACQUIRE, "agent");   // inv L1/L2
  }
  __syncthreads();                       // block waits on tid0's acquire
}

// ================= persistent step kernel (normal launch) =================
// All 7 steps in ONE dispatch. Cross-block dep (proj write -> next-step S read)
// is per-batch only; double-buffered g_proj + per-batch hand barrier.
// Residency: 256 blocks, 60KB LDS, 8 waves -> every block resident, no deadlock.
__global__ __launch_bounds__(512) void k_steps(void* __restrict__ out,
                                               const void* __restrict__ mask){
  int grp = blockIdx.x, tid = threadIdx.x, n0 = grp*4;
  __shared__ __align__(16) float Ssh[4][HH];   // 4 KB
  __shared__ __align__(16) float hsh[4][FD];   // 2 KB
  __shared__ __align__(16) float avs[NN*8];    // 8 KB, persistent adj/valid
  __shared__ __align__(16) char uni[47104];    // 46 KB phase overlay
  float2 (*red)[4][128]  = (float2 (*)[4][128])(uni + 8192);   // S phase
  float  (*part)[4][G3]  = (float  (*)[4][G3])uni;             // gi GEMM
  float  (*Aa)[G3]       = (float  (*)[G3])(uni + 24576);
  float  (*Bs)[FD]       = (float  (*)[FD])(uni + 30720);
  float4 (*ppart)[224]   = (float4 (*)[224])(uni + 32768);     // proj

  int isb = probe_bf16(mask);
  // --- S-phase roles (persistent) ---
  int hp = tid & 127;                  // h-pair: h = 2hp, 2hp+1
  int q  = tid >> 7;                   // j-quarter (wave-uniform)
  int bb = grp >> 6;
  float2 w12 = ((const float2*)g_w1e)[hp];
  // --- gi-GEMM roles ---
  int c96 = tid % 96, sub = tid / 96;
  float bvg = 0.f, bihg = 0.f;
  if (tid < G3){ bvg = g_bv[tid]; bihg = g_bihf[tid]; }
  float deg4[4], msk4[4];
  #pragma unroll
  for (int r = 0; r < 4; ++r){ deg4[r] = g_deg[n0+r]; msk4[r] = g_mask[n0+r]; }
  // --- proj roles ---
  int c = tid & 255, fh = tid >> 8;
  float4 pb = make_float4(0.f,0.f,0.f,0.f);
  if (c < 224) pb = ((const float4*)g_pbias)[c];
  // --- adj/valid tile: load once, persist across steps ---
  ((float4*)avs)[tid] = ((const float4*)(g_av2 + grp*2048))[tid];
  __syncthreads();

  for (int s = 0; s <= STEPS; ++s){
    const float* projr = g_proj + ((s+1)&1)*(NODES*PO);
    float*       projw = g_proj + (s&1)*(NODES*PO);
    int last = (s == STEPS);

    if (s){
      // ---------- S phase: S[i][h] = sum_j relu(Ai+Aj+adj*w1e)*valid ----------
      float2 Ai2[4], acc2[4];
      #pragma unroll
      for (int r = 0; r < 4; ++r){
        Ai2[r] = *(const float2*)(projr + (n0+r)*PO + 2*hp);
        acc2[r] = make_float2(0.f, 0.f);
      }
      const float* ajp = projr + (bb*NN + q*64)*PO + 256 + 2*hp;
      const float4* avp = ((const float4*)avs) + q*128;   // 2 float4 per j
      #pragma unroll 4
      for (int j = 0; j < 64; ++j){
        float2 a2 = *(const float2*)ajp; ajp += PO;
        float4 av01 = avp[2*j];
        float4 av23 = avp[2*j+1];
        float adv[4] = {av01.x, av01.z, av23.x, av23.z};
        float vmv[4] = {av01.y, av01.w, av23.y, av23.w};
        #pragma unroll
        for (int r = 0; r < 4; ++r){
          float vx = Ai2[r].x + a2.x;
          float vy = Ai2[r].y + a2.y;
          vx = fmaf(adv[r], w12.x, vx);
          vy = fmaf(adv[r], w12.y, vy);
          vx = fmaxf(vx, 0.f); vy = fmaxf(vy, 0.f);
          acc2[r].x = fmaf(vx, vmv[r], acc2[r].x);
          acc2[r].y = fmaf(vy, vmv[r], acc2[r].y);
        }
      }
      if (q){
        #pragma unroll
        for (int r = 0; r < 4; ++r) red[q-1][r][hp] = acc2[r];
      }
      __syncthreads();
      if (q == 0){
        #pragma unroll
        for (int r = 0; r < 4; ++r){
          float2 sv = acc2[r];
          float2 p0 = red[0][r][hp], p1 = red[1][r][hp], p2 = red[2][r][hp];
          sv.x += p0.x + p1.x + p2.x;
          sv.y += p0.y + p1.y + p2.y;
          ((float2*)&Ssh[r][0])[hp] = sv;
        }
      }
      __syncthreads();                  // S done; part may overwrite red region

      // ---------- gi GEMM: part = Ssh @ MT (K split 4 ways) ----------
      if (tid < 384){
        int k0 = sub*64;
        float4 acc[4];
        #pragma unroll
        for (int r = 0; r < 4; ++r) acc[r] = make_float4(0.f,0.f,0.f,0.f);
        const float4* MT4 = (const float4*)g_MT;   // [256][96]
        #pragma unroll 4
        for (int k = 0; k < 64; ++k){
          float4 m = MT4[(k0+k)*96 + c96];
          #pragma unroll
          for (int r = 0; r < 4; ++r){
            float sv = Ssh[r][k0+k];
            acc[r].x = fmaf(sv, m.x, acc[r].x);
            acc[r].y = fmaf(sv, m.y, acc[r].y);
            acc[r].z = fmaf(sv, m.z, acc[r].z);
            acc[r].w = fmaf(sv, m.w, acc[r].w);
          }
        }
        #pragma unroll
        for (int r = 0; r < 4; ++r) ((float4*)&part[sub][r][0])[c96] = acc[r];
      }
      __syncthreads();
      if (tid < 384){
        int g = tid;
        #pragma unroll
        for (int r = 0; r < 4; ++r){
          float gi = part[0][r][g] + part[1][r][g] + part[2][r][g] + part[3][r][g]
                   + deg4[r]*bvg + bihg;
          float gh = projr[(n0+r)*PO + 512 + g];
          if (g < 256) Aa[r][g] = gi + gh;
          else { Aa[r][g] = gi; Bs[r][g-256] = gh; }
        }
      }
      __syncthreads();
      // ---------- GRU ----------
      if (tid < 128){
        int f = tid;
        #pragma unroll
        for (int r = 0; r < 4; ++r){
          int node = n0 + r;
          float rr = 1.f/(1.f + __expf(-Aa[r][f]));
          float zz = 1.f/(1.f + __expf(-Aa[r][128+f]));
          float hn = Bs[r][f];
          float narg = Aa[r][256+f] + rr*hn;
          float e = __expf(2.f*narg);
          float nn = 1.f - 2.f/(e + 1.f);
          float hp_ = g_h[node*FD + f];
          float hv = (1.f - zz)*nn + zz*hp_;
          hv *= msk4[r];
          hsh[r][f] = hv;
          g_h[node*FD + f] = hv;
          if (last){
            if (isb) ((bf16*)out)[node*FD + f] = __float2bfloat16(hv);
            else     ((float*)out)[node*FD + f] = hv;
          }
        }
      }
      __syncthreads();
    } else {
      if (tid < 128) ((float4*)&hsh[0][0])[tid] = ((const float4*)(g_h + n0*FD))[tid];
      __syncthreads();
    }

    if (!last){                        // proj for this step's h -> write buffer
      float4 acc[4];
      #pragma unroll
      for (int r = 0; r < 4; ++r) acc[r] = make_float4(0.f,0.f,0.f,0.f);
      if (c < 224){
        const float4* PT4 = (const float4*)g_PT + fh*64*224 + c;
        #pragma unroll 4
        for (int f = 0; f < 64; ++f){
          float4 w = *PT4; PT4 += 224;
          #pragma unroll
          for (int r = 0; r < 4; ++r){
            float hv = hsh[r][fh*64 + f];
            acc[r].x = fmaf(hv, w.x, acc[r].x);
            acc[r].y = fmaf(hv, w.y, acc[r].y);
            acc[r].z = fmaf(hv, w.z, acc[r].z);
            acc[r].w = fmaf(hv, w.w, acc[r].w);
          }
        }
        if (fh == 1){
          #pragma unroll
          for (int r = 0; r < 4; ++r) ppart[r][c] = acc[r];
        }
      }
      __syncthreads();
      if (fh == 0 && c < 224){
        #pragma unroll
        for (int r = 0; r < 4; ++r){
          float4 p = ppart[r][c];
          float4 res;
          res.x = acc[r].x + p.x + pb.x;
          res.y = acc[r].y + p.y + pb.y;
          res.z = acc[r].z + p.z + pb.z;
          res.w = acc[r].w + p.w + pb.w;
          ((float4*)(projw + (n0+r)*PO))[c] = res;
        }
      }
      // per-batch barrier: proj visible to this batch's next S phase
      batch_barrier(bb, 64*(s+1), tid);
    }
  }
}

extern "C" void kernel_launch(void* const* d_in, const int* in_sizes, int n_in,
                              void* d_out, int out_size, void* d_ws, size_t ws_size,
                              hipStream_t stream){
  (void)in_sizes; (void)n_in; (void)out_size; (void)d_ws; (void)ws_size;
  const void* x    = d_in[0];
  const void* adj  = d_in[1];
  const void* mask = d_in[2];
  const void* W1   = d_in[3];
  const void* b1   = d_in[4];
  const void* W2   = d_in[5];
  const void* b2   = d_in[6];
  const void* Wih  = d_in[7];
  const void* bih  = d_in[8];
  const void* Whh  = d_in[9];
  const void* bhh  = d_in[10];

  k_init_a<<<2241, 256, 0, stream>>>(x, adj, mask, W1, b1, Wih, Whh, bhh);
  k_init_MT<<<HH + 1, 384, 0, stream>>>(W2, b2, bih, mask);

  k_steps<<<NODES/4, 512, 0, stream>>>(d_out, mask);
}

// Round 6
// 308.721 us; speedup vs baseline: 1.5439x; 1.2279x over previous
//
#include <hip/hip_runtime.h>
#include <hip/hip_bf16.h>

#define BB 4
#define NN 256           // nodes per batch
#define FD 128
#define HH 256
#define G3 384           // 3*F
#define STEPS 6
#define NODES (BB*NN)    // 1024

typedef __hip_bfloat16 bf16;

// ---- all scratch in device globals (d_ws untrusted) ----
__device__ float g_h[NODES*FD];
__device__ float g_proj[2*NODES*NN];    // double-buffered Aj ONLY (cross-block data)
__device__ float g_av2[NODES*2*NN];     // [grp][j][r][2] : (adj, valid)
__device__ float g_deg[NODES];
__device__ float g_mask[NODES];
__device__ float g_PT[FD*896];          // [f][out]: W1i^T | W1j^T | Whh^T (896 cols)
__device__ float g_pbias[896];
__device__ float g_w1e[HH];
__device__ float g_WihT[HH*G3];         // [h2][g]
__device__ float g_MT[HH*G3];           // [k][g] = (Wih@W2)[g][k]
__device__ float g_bv[G3];
__device__ float g_bihf[G3];
__device__ int   g_bar4[4];             // per-batch barrier counters (zeroed in k_init_a)

__device__ __forceinline__ float b2f(bf16 v){ return __bfloat162float(v); }
__device__ __forceinline__ float ldin(const void* p, int i, int isb){
  return isb ? b2f(((const bf16*)p)[i]) : ((const float*)p)[i];
}
__device__ __forceinline__ int probe_bf16(const void* mask){
  return ((const unsigned short*)mask)[0] == 0x3F80 ? 1 : 0;  // bf16 1.0 halfword
}

// ---- IC-coherent (agent-scope) 8B data ops: coherence rides on the access,
// so the step barrier needs NO cache-maintenance fences (no L2 wb/inv).
__device__ __forceinline__ float2 ldp2(const float* p){
  union { unsigned long long u; float2 f; } cv;
  cv.u = __hip_atomic_load((const unsigned long long*)p,
                           __ATOMIC_RELAXED, __HIP_MEMORY_SCOPE_AGENT);
  return cv.f;
}
__device__ __forceinline__ void stp2(float* p, float x, float y){
  union { unsigned long long u; float2 f; } cv;
  cv.f = make_float2(x, y);
  __hip_atomic_store((unsigned long long*)p, cv.u,
                     __ATOMIC_RELAXED, __HIP_MEMORY_SCOPE_AGENT);
}

// ================= init A: everything input-only =================
// blocks [0,1024): adj row per node | [1024,1472): PT | [1472,1728): WihT
// [1728,2240): h | 2240: small vectors + barrier reset
__global__ __launch_bounds__(256) void k_init_a(
    const void* __restrict__ x, const void* __restrict__ adj,
    const void* __restrict__ mask, const void* __restrict__ W1,
    const void* __restrict__ b1, const void* __restrict__ Wih,
    const void* __restrict__ Whh, const void* __restrict__ bhh){
  int isb = probe_bf16(mask);
  int blk = blockIdx.x, tid = threadIdx.x;
  if (blk < 1024){                       // adj/valid/deg/mask for node = blk
    int node = blk, b = node >> 8, j = tid;
    float mi = ldin(mask, node, isb);
    float mj = ldin(mask, b*NN + j, isb);
    float a  = ldin(adj, node*NN + j, isb);
    float valid = (a > 0.f && mj > 0.f && mi > 0.f) ? 1.f : 0.f;
    int grp = node >> 2, r = node & 3;
    g_av2[grp*2048 + j*8 + r*2]     = a;
    g_av2[grp*2048 + j*8 + r*2 + 1] = valid;
    __shared__ float red[4];
    float s = valid;
    #pragma unroll
    for (int o = 32; o > 0; o >>= 1) s += __shfl_down(s, o, 64);
    if ((j & 63) == 0) red[j >> 6] = s;
    __syncthreads();
    if (j == 0){ g_deg[node] = red[0]+red[1]+red[2]+red[3]; g_mask[node] = mi; }
    return;
  }
  if (blk < 1472){                       // PT
    int i = (blk - 1024)*256 + tid;      // < 114688
    int f = i / 896, o = i % 896;
    float v;
    if (o < 256)       v = ldin(W1, o*257 + f, isb);
    else if (o < 512)  v = ldin(W1, (o-256)*257 + FD + f, isb);
    else               v = ldin(Whh, (o-512)*FD + f, isb);
    g_PT[i] = v;
    return;
  }
  if (blk < 1728){                       // WihT[h2][g] = Wih[g][h2]
    int h2 = blk - 1472;
    for (int g = tid; g < G3; g += 256)
      g_WihT[h2*G3 + g] = ldin(Wih, g*HH + h2, isb);
    return;
  }
  if (blk < 2240){                       // h init
    int i = (blk - 1728)*256 + tid;      // < 131072
    g_h[i] = ldin(x, i, isb);
    return;
  }
  // small vectors + barrier counter reset (runs before k_steps, stream-ordered)
  if (tid < 4) g_bar4[tid] = 0;
  for (int i = tid; i < 896; i += 256){
    float v = 0.f;
    if (i < 256) v = ldin(b1, i, isb);
    else if (i >= 512) v = ldin(bhh, i-512, isb);
    g_pbias[i] = v;
  }
  for (int i = tid; i < HH; i += 256) g_w1e[i] = ldin(W1, i*257 + 256, isb);
  for (int i = tid; i < G3; i += 256) g_bihf[i] = 0.f;  // placeholder; set in MT
}

// ================= init B: MT = (Wih@W2)^T, bv, bihf =================
__global__ __launch_bounds__(384) void k_init_MT(const void* __restrict__ W2,
                                                 const void* __restrict__ b2,
                                                 const void* __restrict__ bih,
                                                 const void* __restrict__ mask){
  int isb = probe_bf16(mask);
  int k = blockIdx.x;     // 0..256 (k==256 -> bv + bihf)
  int g = threadIdx.x;    // 0..383
  __shared__ float col[HH];          // W2[:,k] (or b2)
  if (g < HH){
    col[g] = (k < HH) ? ldin(W2, g*HH + k, isb) : ldin(b2, g, isb);
  }
  __syncthreads();
  const float* wp = g_WihT + g;      // coalesced across threads, stride G3 per h2
  float a0 = 0.f, a1 = 0.f, a2 = 0.f, a3 = 0.f;
  #pragma unroll 8
  for (int h2 = 0; h2 < HH; h2 += 4){
    a0 = fmaf(col[h2+0], wp[(h2+0)*G3], a0);
    a1 = fmaf(col[h2+1], wp[(h2+1)*G3], a1);
    a2 = fmaf(col[h2+2], wp[(h2+2)*G3], a2);
    a3 = fmaf(col[h2+3], wp[(h2+3)*G3], a3);
  }
  float acc = (a0 + a1) + (a2 + a3);
  if (k < HH){
    g_MT[k*G3 + g] = acc;
  } else {
    g_bv[g] = acc;
    g_bihf[g] = ldin(bih, g, isb);
  }
}

// ---- per-batch barrier, fence-free.
// Correct because: (1) __syncthreads drains vmcnt -> this block's Aj
// agent-scope stores have reached the device-coherent point (IC);
// (2) the counter add/loads are agent-scope atomics at the same point;
// (3) readers access Aj ONLY via agent-scope loads (bypass stale caches).
// So no buffer_wbl2/buffer_inv is ever needed -> L2 stays warm with weights.
__device__ __forceinline__ void batch_barrier(int bb, int tgt, int tid){
  __syncthreads();
  if (tid == 0){
    __hip_atomic_fetch_add(&g_bar4[bb], 1, __ATOMIC_RELAXED,
                           __HIP_MEMORY_SCOPE_AGENT);
    while (__hip_atomic_load(&g_bar4[bb], __ATOMIC_RELAXED,
                             __HIP_MEMORY_SCOPE_AGENT) < tgt)
      __builtin_amdgcn_s_sleep(8);
  }
  __syncthreads();
}

// ================= persistent step kernel (normal launch) =================
// Only Aj crosses blocks (via IC, agent-scope ops). Ai/gh/h live in persistent
// LDS (block-private). Weights (MT/PT/w1e/...) stay warm in L2 all 7 steps.
// Static LDS total = 4+2+8+4+6+32 = 56 KB  (<=64 KB limit; 2 blocks/CU).
__global__ __launch_bounds__(512) void k_steps(void* __restrict__ out,
                                               const void* __restrict__ mask){
  int grp = blockIdx.x, tid = threadIdx.x, n0 = grp*4;
  __shared__ __align__(16) float Ssh[4][HH];    // 4 KB
  __shared__ __align__(16) float hsh[4][FD];    // 2 KB  h (block-private, persistent)
  __shared__ __align__(16) float avs[NN*8];     // 8 KB  adj/valid (persistent)
  __shared__ __align__(16) float Aish[4][HH];   // 4 KB  proj Ai (persistent)
  __shared__ __align__(16) float ghsh[4][G3];   // 6 KB  proj gh (persistent)
  __shared__ __align__(16) char uni[32768];     // 32 KB phase overlay
  // S phase:   red   at [8192, 20480)
  // gi GEMM:   part  at [0, 24576) | Aa at [24576, 30720) | Bs at [30720, 32768)
  // proj:      ppart at [0, 14336)   (part/Aa/Bs dead by then; sync-separated)
  float2 (*red)[4][128]  = (float2 (*)[4][128])(uni + 8192);
  float  (*part)[4][G3]  = (float  (*)[4][G3])uni;
  float  (*Aa)[G3]       = (float  (*)[G3])(uni + 24576);
  float  (*Bs)[FD]       = (float  (*)[FD])(uni + 30720);
  float4 (*ppart)[224]   = (float4 (*)[224])uni;

  int isb = probe_bf16(mask);
  // --- S-phase roles (persistent) ---
  int hp = tid & 127;                  // h-pair: h = 2hp, 2hp+1
  int q  = tid >> 7;                   // j-quarter (wave-uniform)
  int bb = grp >> 6;
  float2 w12 = ((const float2*)g_w1e)[hp];
  // --- gi-GEMM roles ---
  int c96 = tid % 96, sub = tid / 96;
  float bvg = 0.f, bihg = 0.f;
  if (tid < G3){ bvg = g_bv[tid]; bihg = g_bihf[tid]; }
  float deg4[4], msk4[4];
  #pragma unroll
  for (int r = 0; r < 4; ++r){ deg4[r] = g_deg[n0+r]; msk4[r] = g_mask[n0+r]; }
  // --- proj roles ---
  int c = tid & 255, fh = tid >> 8;
  float4 pb = make_float4(0.f,0.f,0.f,0.f);
  if (c < 224) pb = ((const float4*)g_pbias)[c];
  // --- adj/valid tile + h: load once, persist across steps ---
  ((float4*)avs)[tid] = ((const float4*)(g_av2 + grp*2048))[tid];
  if (tid < 128) ((float4*)&hsh[0][0])[tid] = ((const float4*)(g_h + n0*FD))[tid];
  __syncthreads();

  for (int s = 0; s <= STEPS; ++s){
    const float* projr = g_proj + ((s+1)&1)*(NODES*NN);
    float*       projw = g_proj + (s&1)*(NODES*NN);
    int last = (s == STEPS);

    if (s){
      // ---------- S phase: S[i][h] = sum_j relu(Ai+Aj+adj*w1e)*valid ----------
      float2 Ai2[4], acc2[4];
      #pragma unroll
      for (int r = 0; r < 4; ++r){
        Ai2[r] = ((const float2*)&Aish[r][0])[hp];   // LDS (own block's proj Ai)
        acc2[r] = make_float2(0.f, 0.f);
      }
      const float* ajp = projr + (bb*NN + q*64)*NN + 2*hp;   // Aj rows, stride NN
      const float4* avp = ((const float4*)avs) + q*128;      // 2 float4 per j
      #pragma unroll 4
      for (int j = 0; j < 64; ++j){
        float2 a2 = ldp2(ajp); ajp += NN;            // IC-coherent Aj read
        float4 av01 = avp[2*j];
        float4 av23 = avp[2*j+1];
        float adv[4] = {av01.x, av01.z, av23.x, av23.z};
        float vmv[4] = {av01.y, av01.w, av23.y, av23.w};
        #pragma unroll
        for (int r = 0; r < 4; ++r){
          float vx = Ai2[r].x + a2.x;
          float vy = Ai2[r].y + a2.y;
          vx = fmaf(adv[r], w12.x, vx);
          vy = fmaf(adv[r], w12.y, vy);
          vx = fmaxf(vx, 0.f); vy = fmaxf(vy, 0.f);
          acc2[r].x = fmaf(vx, vmv[r], acc2[r].x);
          acc2[r].y = fmaf(vy, vmv[r], acc2[r].y);
        }
      }
      if (q){
        #pragma unroll
        for (int r = 0; r < 4; ++r) red[q-1][r][hp] = acc2[r];
      }
      __syncthreads();
      if (q == 0){
        #pragma unroll
        for (int r = 0; r < 4; ++r){
          float2 sv = acc2[r];
          float2 p0 = red[0][r][hp], p1 = red[1][r][hp], p2 = red[2][r][hp];
          sv.x += p0.x + p1.x + p2.x;
          sv.y += p0.y + p1.y + p2.y;
          ((float2*)&Ssh[r][0])[hp] = sv;
        }
      }
      __syncthreads();                  // S done; part may overwrite red region

      // ---------- gi GEMM: part = Ssh @ MT (K split 4 ways) ----------
      if (tid < 384){
        int k0 = sub*64;
        float4 acc[4];
        #pragma unroll
        for (int r = 0; r < 4; ++r) acc[r] = make_float4(0.f,0.f,0.f,0.f);
        const float4* MT4 = (const float4*)g_MT;   // [256][96]
        #pragma unroll 4
        for (int k = 0; k < 64; ++k){
          float4 m = MT4[(k0+k)*96 + c96];
          #pragma unroll
          for (int r = 0; r < 4; ++r){
            float sv = Ssh[r][k0+k];
            acc[r].x = fmaf(sv, m.x, acc[r].x);
            acc[r].y = fmaf(sv, m.y, acc[r].y);
            acc[r].z = fmaf(sv, m.z, acc[r].z);
            acc[r].w = fmaf(sv, m.w, acc[r].w);
          }
        }
        #pragma unroll
        for (int r = 0; r < 4; ++r) ((float4*)&part[sub][r][0])[c96] = acc[r];
      }
      __syncthreads();
      if (tid < 384){
        int g = tid;
        #pragma unroll
        for (int r = 0; r < 4; ++r){
          float gi = part[0][r][g] + part[1][r][g] + part[2][r][g] + part[3][r][g]
                   + deg4[r]*bvg + bihg;
          float gh = ghsh[r][g];                     // LDS (own block's proj gh)
          if (g < 256) Aa[r][g] = gi + gh;
          else { Aa[r][g] = gi; Bs[r][g-256] = gh; }
        }
      }
      __syncthreads();
      // ---------- GRU (h fully in LDS; no global h traffic) ----------
      if (tid < 128){
        int f = tid;
        #pragma unroll
        for (int r = 0; r < 4; ++r){
          int node = n0 + r;
          float rr = 1.f/(1.f + __expf(-Aa[r][f]));
          float zz = 1.f/(1.f + __expf(-Aa[r][128+f]));
          float hn = Bs[r][f];
          float narg = Aa[r][256+f] + rr*hn;
          float e = __expf(2.f*narg);
          float nn = 1.f - 2.f/(e + 1.f);
          float hp_ = hsh[r][f];                     // previous h (LDS)
          float hv = (1.f - zz)*nn + zz*hp_;
          hv *= msk4[r];
          hsh[r][f] = hv;
          if (last){
            if (isb) ((bf16*)out)[node*FD + f] = __float2bfloat16(hv);
            else     ((float*)out)[node*FD + f] = hv;
          }
        }
      }
      __syncthreads();
    }

    if (!last){                        // proj: Ai->LDS, Aj->IC, gh->LDS
      float4 acc[4];
      #pragma unroll
      for (int r = 0; r < 4; ++r) acc[r] = make_float4(0.f,0.f,0.f,0.f);
      if (c < 224){
        const float4* PT4 = (const float4*)g_PT + fh*64*224 + c;
        #pragma unroll 4
        for (int f = 0; f < 64; ++f){
          float4 w = *PT4; PT4 += 224;
          #pragma unroll
          for (int r = 0; r < 4; ++r){
            float hv = hsh[r][fh*64 + f];
            acc[r].x = fmaf(hv, w.x, acc[r].x);
            acc[r].y = fmaf(hv, w.y, acc[r].y);
            acc[r].z = fmaf(hv, w.z, acc[r].z);
            acc[r].w = fmaf(hv, w.w, acc[r].w);
          }
        }
        if (fh == 1){
          #pragma unroll
          for (int r = 0; r < 4; ++r) ppart[r][c] = acc[r];
        }
      }
      __syncthreads();
      if (fh == 0 && c < 224){
        #pragma unroll
        for (int r = 0; r < 4; ++r){
          float4 p = ppart[r][c];
          float4 res;
          res.x = acc[r].x + p.x + pb.x;
          res.y = acc[r].y + p.y + pb.y;
          res.z = acc[r].z + p.z + pb.z;
          res.w = acc[r].w + p.w + pb.w;
          if (c < 64){                 // Ai cols [4c,4c+4) -> LDS
            ((float4*)&Aish[r][0])[c] = res;
          } else if (c < 128){         // Aj cols -> IC (cross-block)
            int cc = c - 64;
            stp2(projw + (n0+r)*NN + 4*cc,     res.x, res.y);
            stp2(projw + (n0+r)*NN + 4*cc + 2, res.z, res.w);
          } else {                     // gh cols -> LDS
            ((float4*)&ghsh[r][0])[c-128] = res;
          }
        }
      }
      // per-batch barrier: Aj visible to this batch's next S phase
      batch_barrier(bb, 64*(s+1), tid);
    }
  }
}

extern "C" void kernel_launch(void* const* d_in, const int* in_sizes, int n_in,
                              void* d_out, int out_size, void* d_ws, size_t ws_size,
                              hipStream_t stream){
  (void)in_sizes; (void)n_in; (void)out_size; (void)d_ws; (void)ws_size;
  const void* x    = d_in[0];
  const void* adj  = d_in[1];
  const void* mask = d_in[2];
  const void* W1   = d_in[3];
  const void* b1   = d_in[4];
  const void* W2   = d_in[5];
  const void* b2   = d_in[6];
  const void* Wih  = d_in[7];
  const void* bih  = d_in[8];
  const void* Whh  = d_in[9];
  const void* bhh  = d_in[10];

  k_init_a<<<2241, 256, 0, stream>>>(x, adj, mask, W1, b1, Wih, Whh, bhh);
  k_init_MT<<<HH + 1, 384, 0, stream>>>(W2, b2, bih, mask);

  k_steps<<<NODES/4, 512, 0, stream>>>(d_out, mask);
}

// Round 7
// 234.341 us; speedup vs baseline: 2.0339x; 1.3174x over previous
//
#include <hip/hip_runtime.h>
#include <hip/hip_bf16.h>

#define BB 4
#define NN 256           // nodes per batch
#define FD 128
#define HH 256
#define G3 384           // 3*F
#define STEPS 6
#define PO 896           // proj width: Ai[0:256) | Aj[256:512) | gh[512:896)
#define NODES (BB*NN)    // 1024

typedef __hip_bfloat16 bf16;

// ---- all scratch in device globals (d_ws untrusted) ----
__device__ float g_h[NODES*FD];
__device__ float g_proj[2*NODES*PO];    // double-buffered across steps
__device__ float g_av2[NODES*2*NN];     // [node>>1][j][r2][2] : (adj, valid)
__device__ float g_deg[NODES];
__device__ float g_mask[NODES];
__device__ float g_PT[FD*PO];           // [f][out]: W1i^T | W1j^T | Whh^T
__device__ float g_pbias[PO];
__device__ float g_w1e[HH];
__device__ float g_WihT[HH*G3];         // [h2][g]
__device__ float g_MT[HH*G3];           // [k][g] = (Wih@W2)[g][k]
__device__ float g_bv[G3];
__device__ float g_bihf[G3];

__device__ __forceinline__ float b2f(bf16 v){ return __bfloat162float(v); }
__device__ __forceinline__ float ldin(const void* p, int i, int isb){
  return isb ? b2f(((const bf16*)p)[i]) : ((const float*)p)[i];
}
__device__ __forceinline__ int probe_bf16(const void* mask){
  return ((const unsigned short*)mask)[0] == 0x3F80 ? 1 : 0;  // bf16 1.0 halfword
}

// ================= init A: everything input-only =================
// blocks [0,1024): adj row per node | [1024,1472): PT | [1472,1728): WihT
// [1728,2240): h | 2240: small vectors
__global__ __launch_bounds__(256) void k_init_a(
    const void* __restrict__ x, const void* __restrict__ adj,
    const void* __restrict__ mask, const void* __restrict__ W1,
    const void* __restrict__ b1, const void* __restrict__ Wih,
    const void* __restrict__ Whh, const void* __restrict__ bhh){
  int isb = probe_bf16(mask);
  int blk = blockIdx.x, tid = threadIdx.x;
  if (blk < 1024){                       // adj/valid/deg/mask for node = blk
    int node = blk, b = node >> 8, j = tid;
    float mi = ldin(mask, node, isb);
    float mj = ldin(mask, b*NN + j, isb);
    float a  = ldin(adj, node*NN + j, isb);
    float valid = (a > 0.f && mj > 0.f && mi > 0.f) ? 1.f : 0.f;
    int g2 = node >> 1, r2 = node & 1;   // 2-node groups for k_step
    g_av2[g2*1024 + j*4 + r2*2]     = a;
    g_av2[g2*1024 + j*4 + r2*2 + 1] = valid;
    __shared__ float red[4];
    float s = valid;
    #pragma unroll
    for (int o = 32; o > 0; o >>= 1) s += __shfl_down(s, o, 64);
    if ((j & 63) == 0) red[j >> 6] = s;
    __syncthreads();
    if (j == 0){ g_deg[node] = red[0]+red[1]+red[2]+red[3]; g_mask[node] = mi; }
    return;
  }
  if (blk < 1472){                       // PT
    int i = (blk - 1024)*256 + tid;      // < 114688
    int f = i / PO, o = i % PO;
    float v;
    if (o < 256)       v = ldin(W1, o*257 + f, isb);
    else if (o < 512)  v = ldin(W1, (o-256)*257 + FD + f, isb);
    else               v = ldin(Whh, (o-512)*FD + f, isb);
    g_PT[i] = v;
    return;
  }
  if (blk < 1728){                       // WihT[h2][g] = Wih[g][h2]
    int h2 = blk - 1472;
    for (int g = tid; g < G3; g += 256)
      g_WihT[h2*G3 + g] = ldin(Wih, g*HH + h2, isb);
    return;
  }
  if (blk < 2240){                       // h init
    int i = (blk - 1728)*256 + tid;      // < 131072
    g_h[i] = ldin(x, i, isb);
    return;
  }
  // small vectors
  for (int i = tid; i < PO; i += 256){
    float v = 0.f;
    if (i < 256) v = ldin(b1, i, isb);
    else if (i >= 512) v = ldin(bhh, i-512, isb);
    g_pbias[i] = v;
  }
  for (int i = tid; i < HH; i += 256) g_w1e[i] = ldin(W1, i*257 + 256, isb);
}

// ================= init B: MT = (Wih@W2)^T + bv/bihf + step-0 proj ==========
// blocks [0,256): MT col | 256: bv+bihf | [257,769): proj0 for 2 nodes each
// (proj0 independent of MT blocks: reads g_h/g_PT/g_pbias from k_init_a.)
__global__ __launch_bounds__(384) void k_init_MT(const void* __restrict__ W2,
                                                 const void* __restrict__ b2,
                                                 const void* __restrict__ bih,
                                                 const void* __restrict__ mask){
  int isb = probe_bf16(mask);
  int k = blockIdx.x;
  int g = threadIdx.x;    // 0..383
  __shared__ float col[HH];
  __shared__ float h2[2][FD];
  if (k < 257){
    if (g < HH){
      col[g] = (k < HH) ? ldin(W2, g*HH + k, isb) : ldin(b2, g, isb);
    }
    __syncthreads();
    const float* wp = g_WihT + g;
    float a0 = 0.f, a1 = 0.f, a2 = 0.f, a3 = 0.f;
    #pragma unroll 8
    for (int h2_ = 0; h2_ < HH; h2_ += 4){
      a0 = fmaf(col[h2_+0], wp[(h2_+0)*G3], a0);
      a1 = fmaf(col[h2_+1], wp[(h2_+1)*G3], a1);
      a2 = fmaf(col[h2_+2], wp[(h2_+2)*G3], a2);
      a3 = fmaf(col[h2_+3], wp[(h2_+3)*G3], a3);
    }
    float acc = (a0 + a1) + (a2 + a3);
    if (k < HH){
      g_MT[k*G3 + g] = acc;
    } else {
      g_bv[g] = acc;
      g_bihf[g] = ldin(bih, g, isb);
    }
    return;
  }
  // ---- proj0: write proj buffer 0 for nodes [n0, n0+2) ----
  int n0 = (k - 257)*2;
  if (g < 64) ((float4*)&h2[0][0])[g] = ((const float4*)(g_h + n0*FD))[g];
  __syncthreads();
  if (g < 224){
    float4 pbv = ((const float4*)g_pbias)[g];
    float4 a0 = make_float4(0.f,0.f,0.f,0.f), a1 = a0;
    const float4* PT4 = (const float4*)g_PT + g;
    #pragma unroll 4
    for (int f = 0; f < FD; ++f){
      float4 w = PT4[f*224];
      float v0 = h2[0][f], v1 = h2[1][f];
      a0.x = fmaf(v0, w.x, a0.x); a0.y = fmaf(v0, w.y, a0.y);
      a0.z = fmaf(v0, w.z, a0.z); a0.w = fmaf(v0, w.w, a0.w);
      a1.x = fmaf(v1, w.x, a1.x); a1.y = fmaf(v1, w.y, a1.y);
      a1.z = fmaf(v1, w.z, a1.z); a1.w = fmaf(v1, w.w, a1.w);
    }
    a0.x += pbv.x; a0.y += pbv.y; a0.z += pbv.z; a0.w += pbv.w;
    a1.x += pbv.x; a1.y += pbv.y; a1.z += pbv.z; a1.w += pbv.w;
    ((float4*)(g_proj + n0*PO))[g]     = a0;
    ((float4*)(g_proj + (n0+1)*PO))[g] = a1;
  }
}

// ================= per-step fused kernel: 2 nodes/block, 512 blocks ==========
// 16 waves/CU (2 blocks x 8 waves) for latency hiding. LDS ~30 KB.
__global__ __launch_bounds__(512, 4) void k_step(void* __restrict__ out,
                                                 const void* __restrict__ mask,
                                                 int last, int roff, int woff){
  int grp = blockIdx.x, tid = threadIdx.x, n0 = grp*2;
  __shared__ __align__(16) float Ssh[2][HH];    // 2 KB
  __shared__ __align__(16) float hsh[2][FD];    // 1 KB
  __shared__ __align__(16) float avs[NN*4];     // 4 KB  [j][r2][2]
  __shared__ __align__(16) char uni[22528];     // 22 KB phase overlay
  // S:     red   [7][2][64] float4  at [0, 14336)
  // GEMM:  part  [4][2][G3]         at [0, 12288)
  //        Aa    [2][G3]            at [16384, 19456)
  //        Bs    [2][FD]            at [20480, 21504)
  // proj:  ppart [2][224] float4    at [0, 7168)
  float4 (*red)[2][64]  = (float4 (*)[2][64])uni;
  float  (*part)[2][G3] = (float  (*)[2][G3])uni;
  float  (*Aa)[G3]      = (float  (*)[G3])(uni + 16384);
  float  (*Bs)[FD]      = (float  (*)[FD])(uni + 20480);
  float4 (*ppart)[224]  = (float4 (*)[224])uni;

  const float* projr = g_proj + roff;
  float*       projw = g_proj + woff;
  int isb = probe_bf16(mask);
  int hq = tid & 63;                   // h-quad: h = 4hq..4hq+3
  int q  = tid >> 6;                   // j-octant (wave-uniform)
  int bb = grp >> 7;                   // batch (128 blocks per batch)

  // adj/valid tile for this 2-node group
  ((float2*)avs)[tid] = ((const float2*)(g_av2 + grp*1024))[tid];

  // ---------- S phase: S[i][h] = sum_j relu(Ai+Aj+adj*w1e)*valid ----------
  float4 w14 = ((const float4*)g_w1e)[hq];
  float4 Ai4[2], acc4[2];
  #pragma unroll
  for (int r = 0; r < 2; ++r){
    Ai4[r] = *(const float4*)(projr + (n0+r)*PO + 4*hq);
    acc4[r] = make_float4(0.f, 0.f, 0.f, 0.f);
  }
  __syncthreads();
  const float* ajp = projr + (bb*NN + q*32)*PO + 256 + 4*hq;
  const float4* avp = ((const float4*)avs) + q*32;
  #pragma unroll 4
  for (int j = 0; j < 32; ++j){
    float4 a4 = *(const float4*)ajp; ajp += PO;
    float4 av = avp[j];                // {adj0, val0, adj1, val1} (broadcast)
    float adv[2] = {av.x, av.z};
    float vmv[2] = {av.y, av.w};
    #pragma unroll
    for (int r = 0; r < 2; ++r){
      float vx = Ai4[r].x + a4.x;
      float vy = Ai4[r].y + a4.y;
      float vz = Ai4[r].z + a4.z;
      float vw = Ai4[r].w + a4.w;
      vx = fmaf(adv[r], w14.x, vx);
      vy = fmaf(adv[r], w14.y, vy);
      vz = fmaf(adv[r], w14.z, vz);
      vw = fmaf(adv[r], w14.w, vw);
      vx = fmaxf(vx, 0.f); vy = fmaxf(vy, 0.f);
      vz = fmaxf(vz, 0.f); vw = fmaxf(vw, 0.f);
      acc4[r].x = fmaf(vx, vmv[r], acc4[r].x);
      acc4[r].y = fmaf(vy, vmv[r], acc4[r].y);
      acc4[r].z = fmaf(vz, vmv[r], acc4[r].z);
      acc4[r].w = fmaf(vw, vmv[r], acc4[r].w);
    }
  }
  if (q){
    #pragma unroll
    for (int r = 0; r < 2; ++r) red[q-1][r][hq] = acc4[r];
  }
  __syncthreads();
  if (q == 0){
    #pragma unroll
    for (int r = 0; r < 2; ++r){
      float4 sv = acc4[r];
      #pragma unroll
      for (int p = 0; p < 7; ++p){
        float4 pv = red[p][r][hq];
        sv.x += pv.x; sv.y += pv.y; sv.z += pv.z; sv.w += pv.w;
      }
      ((float4*)&Ssh[r][0])[hq] = sv;
    }
  }
  __syncthreads();                     // S done; part may overwrite red

  // ---------- gi GEMM: part = Ssh @ MT (K split 4 ways, 384 threads) --------
  if (tid < 384){
    int c96 = tid % 96, sub = tid / 96;
    int k0 = sub*64;
    float4 acc0 = make_float4(0.f,0.f,0.f,0.f), acc1 = acc0;
    const float4* MT4 = (const float4*)g_MT;   // [256][96]
    #pragma unroll 8
    for (int k = 0; k < 64; ++k){
      float4 m = MT4[(k0+k)*96 + c96];
      float s0 = Ssh[0][k0+k], s1 = Ssh[1][k0+k];
      acc0.x = fmaf(s0, m.x, acc0.x); acc0.y = fmaf(s0, m.y, acc0.y);
      acc0.z = fmaf(s0, m.z, acc0.z); acc0.w = fmaf(s0, m.w, acc0.w);
      acc1.x = fmaf(s1, m.x, acc1.x); acc1.y = fmaf(s1, m.y, acc1.y);
      acc1.z = fmaf(s1, m.z, acc1.z); acc1.w = fmaf(s1, m.w, acc1.w);
    }
    ((float4*)&part[sub][0][0])[c96] = acc0;
    ((float4*)&part[sub][1][0])[c96] = acc1;
  }
  __syncthreads();
  if (tid < 384){
    int g = tid;
    float bvg = g_bv[g], bihg = g_bihf[g];
    #pragma unroll
    for (int r = 0; r < 2; ++r){
      float gi = part[0][r][g] + part[1][r][g] + part[2][r][g] + part[3][r][g]
               + g_deg[n0+r]*bvg + bihg;
      float gh = projr[(n0+r)*PO + 512 + g];
      if (g < 256) Aa[r][g] = gi + gh;
      else { Aa[r][g] = gi; Bs[r][g-256] = gh; }
    }
  }
  __syncthreads();
  // ---------- GRU ----------
  if (tid < 128){
    int f = tid;
    #pragma unroll
    for (int r = 0; r < 2; ++r){
      int node = n0 + r;
      float rr = 1.f/(1.f + __expf(-Aa[r][f]));
      float zz = 1.f/(1.f + __expf(-Aa[r][128+f]));
      float hn = Bs[r][f];
      float narg = Aa[r][256+f] + rr*hn;
      float e = __expf(2.f*narg);
      float nn = 1.f - 2.f/(e + 1.f);
      float hp_ = g_h[node*FD + f];
      float hv = (1.f - zz)*nn + zz*hp_;
      hv *= g_mask[node];
      hsh[r][f] = hv;
      g_h[node*FD + f] = hv;
      if (last){
        if (isb) ((bf16*)out)[node*FD + f] = __float2bfloat16(hv);
        else     ((float*)out)[node*FD + f] = hv;
      }
    }
  }
  __syncthreads();

  if (!last){                          // proj for this step's h -> write buffer
    int c = tid & 255, fh = tid >> 8;  // f-split for parallelism
    float4 a0 = make_float4(0.f,0.f,0.f,0.f), a1 = a0;
    if (c < 224){
      const float4* PT4 = (const float4*)g_PT + fh*64*224 + c;
      #pragma unroll 4
      for (int f = 0; f < 64; ++f){
        float4 w = *PT4; PT4 += 224;
        float v0 = hsh[0][fh*64 + f], v1 = hsh[1][fh*64 + f];
        a0.x = fmaf(v0, w.x, a0.x); a0.y = fmaf(v0, w.y, a0.y);
        a0.z = fmaf(v0, w.z, a0.z); a0.w = fmaf(v0, w.w, a0.w);
        a1.x = fmaf(v1, w.x, a1.x); a1.y = fmaf(v1, w.y, a1.y);
        a1.z = fmaf(v1, w.z, a1.z); a1.w = fmaf(v1, w.w, a1.w);
      }
      if (fh == 1){ ppart[0][c] = a0; ppart[1][c] = a1; }
    }
    __syncthreads();
    if (fh == 0 && c < 224){
      float4 pbv = ((const float4*)g_pbias)[c];
      float4 p0 = ppart[0][c], p1 = ppart[1][c];
      float4 r0, r1;
      r0.x = a0.x + p0.x + pbv.x; r0.y = a0.y + p0.y + pbv.y;
      r0.z = a0.z + p0.z + pbv.z; r0.w = a0.w + p0.w + pbv.w;
      r1.x = a1.x + p1.x + pbv.x; r1.y = a1.y + p1.y + pbv.y;
      r1.z = a1.z + p1.z + pbv.z; r1.w = a1.w + p1.w + pbv.w;
      ((float4*)(projw + n0*PO))[c]     = r0;
      ((float4*)(projw + (n0+1)*PO))[c] = r1;
    }
  }
}

extern "C" void kernel_launch(void* const* d_in, const int* in_sizes, int n_in,
                              void* d_out, int out_size, void* d_ws, size_t ws_size,
                              hipStream_t stream){
  (void)in_sizes; (void)n_in; (void)out_size; (void)d_ws; (void)ws_size;
  const void* x    = d_in[0];
  const void* adj  = d_in[1];
  const void* mask = d_in[2];
  const void* W1   = d_in[3];
  const void* b1   = d_in[4];
  const void* W2   = d_in[5];
  const void* b2   = d_in[6];
  const void* Wih  = d_in[7];
  const void* bih  = d_in[8];
  const void* Whh  = d_in[9];
  const void* bhh  = d_in[10];

  k_init_a<<<2241, 256, 0, stream>>>(x, adj, mask, W1, b1, Wih, Whh, bhh);
  k_init_MT<<<257 + 512, 384, 0, stream>>>(W2, b2, bih, mask);   // + step-0 proj

  for (int s = 1; s <= STEPS; ++s){
    int woff = (s & 1) * NODES * PO;          // write buffer for step s
    int roff = ((s + 1) & 1) * NODES * PO;    // read buffer (step s-1's write)
    k_step<<<512, 512, 0, stream>>>(d_out, mask, s == STEPS ? 1 : 0, roff, woff);
  }
}

// Round 8
// 217.776 us; speedup vs baseline: 2.1886x; 1.0761x over previous
//
#include <hip/hip_runtime.h>
#include <hip/hip_bf16.h>

#define BB 4
#define NN 256           // nodes per batch
#define FD 128
#define HH 256
#define G3 384           // 3*F
#define STEPS 6
#define PO 896           // proj width: Ai[0:256) | Aj[256:512) | gh[512:896)
#define NODES (BB*NN)    // 1024

typedef __hip_bfloat16 bf16;

// ---- all scratch in device globals (d_ws untrusted) ----
__device__ float g_h[NODES*FD];
__device__ float g_proj[2*NODES*PO];    // double-buffered across steps
__device__ float g_av2[NODES*2*NN];     // [node>>2][j][r4][2] : (adj, valid)
__device__ float g_deg[NODES];
__device__ float g_mask[NODES];
__device__ float g_PT[FD*PO];           // [f][out]: W1i^T | W1j^T | Whh^T
__device__ float g_pbias[PO];
__device__ float g_w1e[HH];
__device__ float g_WihT[HH*G3];         // [h2][g]
__device__ float g_MT[HH*G3];           // [k][g] = (Wih@W2)[g][k]
__device__ float g_bv[G3];
__device__ float g_bihf[G3];

__device__ __forceinline__ float b2f(bf16 v){ return __bfloat162float(v); }
__device__ __forceinline__ float ldin(const void* p, int i, int isb){
  return isb ? b2f(((const bf16*)p)[i]) : ((const float*)p)[i];
}
__device__ __forceinline__ int probe_bf16(const void* mask){
  return ((const unsigned short*)mask)[0] == 0x3F80 ? 1 : 0;  // bf16 1.0 halfword
}

// ================= init A: everything input-only =================
// blocks [0,1024): adj row per node | [1024,1472): PT | [1472,1728): WihT
// [1728,2240): h | 2240: small vectors
__global__ __launch_bounds__(256) void k_init_a(
    const void* __restrict__ x, const void* __restrict__ adj,
    const void* __restrict__ mask, const void* __restrict__ W1,
    const void* __restrict__ b1, const void* __restrict__ Wih,
    const void* __restrict__ Whh, const void* __restrict__ bhh){
  int isb = probe_bf16(mask);
  int blk = blockIdx.x, tid = threadIdx.x;
  if (blk < 1024){                       // adj/valid/deg/mask for node = blk
    int node = blk, b = node >> 8, j = tid;
    float mi = ldin(mask, node, isb);
    float mj = ldin(mask, b*NN + j, isb);
    float a  = ldin(adj, node*NN + j, isb);
    float valid = (a > 0.f && mj > 0.f && mi > 0.f) ? 1.f : 0.f;
    int grp = node >> 2, r = node & 3;   // 4-node groups for k_step
    g_av2[grp*2048 + j*8 + r*2]     = a;
    g_av2[grp*2048 + j*8 + r*2 + 1] = valid;
    __shared__ float red[4];
    float s = valid;
    #pragma unroll
    for (int o = 32; o > 0; o >>= 1) s += __shfl_down(s, o, 64);
    if ((j & 63) == 0) red[j >> 6] = s;
    __syncthreads();
    if (j == 0){ g_deg[node] = red[0]+red[1]+red[2]+red[3]; g_mask[node] = mi; }
    return;
  }
  if (blk < 1472){                       // PT
    int i = (blk - 1024)*256 + tid;      // < 114688
    int f = i / PO, o = i % PO;
    float v;
    if (o < 256)       v = ldin(W1, o*257 + f, isb);
    else if (o < 512)  v = ldin(W1, (o-256)*257 + FD + f, isb);
    else               v = ldin(Whh, (o-512)*FD + f, isb);
    g_PT[i] = v;
    return;
  }
  if (blk < 1728){                       // WihT[h2][g] = Wih[g][h2]
    int h2 = blk - 1472;
    for (int g = tid; g < G3; g += 256)
      g_WihT[h2*G3 + g] = ldin(Wih, g*HH + h2, isb);
    return;
  }
  if (blk < 2240){                       // h init
    int i = (blk - 1728)*256 + tid;      // < 131072
    g_h[i] = ldin(x, i, isb);
    return;
  }
  // small vectors
  for (int i = tid; i < PO; i += 256){
    float v = 0.f;
    if (i < 256) v = ldin(b1, i, isb);
    else if (i >= 512) v = ldin(bhh, i-512, isb);
    g_pbias[i] = v;
  }
  for (int i = tid; i < HH; i += 256) g_w1e[i] = ldin(W1, i*257 + 256, isb);
}

// ================= init B: MT = (Wih@W2)^T + bv/bihf + step-0 proj ==========
// blocks [0,256): MT col | 256: bv+bihf | [257,513): proj0 for 4 nodes each
__global__ __launch_bounds__(384) void k_init_MT(const void* __restrict__ W2,
                                                 const void* __restrict__ b2,
                                                 const void* __restrict__ bih,
                                                 const void* __restrict__ mask){
  int isb = probe_bf16(mask);
  int k = blockIdx.x;
  int g = threadIdx.x;    // 0..383
  __shared__ float col[HH];
  __shared__ float h4[4][FD];
  if (k < 257){
    if (g < HH){
      col[g] = (k < HH) ? ldin(W2, g*HH + k, isb) : ldin(b2, g, isb);
    }
    __syncthreads();
    const float* wp = g_WihT + g;
    float a0 = 0.f, a1 = 0.f, a2 = 0.f, a3 = 0.f;
    #pragma unroll 8
    for (int h2 = 0; h2 < HH; h2 += 4){
      a0 = fmaf(col[h2+0], wp[(h2+0)*G3], a0);
      a1 = fmaf(col[h2+1], wp[(h2+1)*G3], a1);
      a2 = fmaf(col[h2+2], wp[(h2+2)*G3], a2);
      a3 = fmaf(col[h2+3], wp[(h2+3)*G3], a3);
    }
    float acc = (a0 + a1) + (a2 + a3);
    if (k < HH){
      g_MT[k*G3 + g] = acc;
    } else {
      g_bv[g] = acc;
      g_bihf[g] = ldin(bih, g, isb);
    }
    return;
  }
  // ---- proj0: write proj buffer 0 for nodes [n0, n0+4) ----
  int n0 = (k - 257)*4;
  if (g < 128) ((float4*)&h4[0][0])[g] = ((const float4*)(g_h + n0*FD))[g];
  __syncthreads();
  if (g < 224){
    float4 pbv = ((const float4*)g_pbias)[g];
    float4 a[4];
    #pragma unroll
    for (int r = 0; r < 4; ++r) a[r] = make_float4(0.f,0.f,0.f,0.f);
    const float4* PT4 = (const float4*)g_PT + g;
    #pragma unroll 4
    for (int f = 0; f < FD; ++f){
      float4 w = PT4[f*224];
      #pragma unroll
      for (int r = 0; r < 4; ++r){
        float v = h4[r][f];
        a[r].x = fmaf(v, w.x, a[r].x);
        a[r].y = fmaf(v, w.y, a[r].y);
        a[r].z = fmaf(v, w.z, a[r].z);
        a[r].w = fmaf(v, w.w, a[r].w);
      }
    }
    #pragma unroll
    for (int r = 0; r < 4; ++r){
      a[r].x += pbv.x; a[r].y += pbv.y; a[r].z += pbv.z; a[r].w += pbv.w;
      ((float4*)(g_proj + (n0+r)*PO))[g] = a[r];
    }
  }
}

// ================= per-step fused kernel: 4 nodes/block, 256 blocks ==========
// 1 block/CU minimizes per-CU weight streaming (MT+PT = 832 KB/CU/step).
// LDS = 4+2+8+32 = 46 KB.
__global__ __launch_bounds__(512) void k_step(void* __restrict__ out,
                                              const void* __restrict__ mask,
                                              int last, int roff, int woff){
  int grp = blockIdx.x, tid = threadIdx.x, n0 = grp*4;
  __shared__ __align__(16) float Ssh[4][HH];    // 4 KB
  __shared__ __align__(16) float hsh[4][FD];    // 2 KB
  __shared__ __align__(16) float avs[NN*8];     // 8 KB  [j][r4][2]
  __shared__ __align__(16) char uni[32768];     // 32 KB phase overlay
  // S:     red   [7][4][64] float4  at [0, 28672)
  // GEMM:  part  [4][4][G3]         at [0, 24576)
  //        Aa    [4][G3]            at [24576, 30720)
  //        Bs    [4][FD]            at [30720, 32768)
  // proj:  ppart [4][224] float4    at [0, 14336)
  float4 (*red)[4][64]  = (float4 (*)[4][64])uni;
  float  (*part)[4][G3] = (float  (*)[4][G3])uni;
  float  (*Aa)[G3]      = (float  (*)[G3])(uni + 24576);
  float  (*Bs)[FD]      = (float  (*)[FD])(uni + 30720);
  float4 (*ppart)[224]  = (float4 (*)[224])uni;

  const float* projr = g_proj + roff;
  float*       projw = g_proj + woff;
  int isb = probe_bf16(mask);
  int hq = tid & 63;                   // h-quad: h = 4hq..4hq+3
  int q  = tid >> 6;                   // j-octant (wave-uniform)
  int bb = grp >> 6;                   // batch (64 blocks per batch)

  // adj/valid tile for this 4-node group
  ((float4*)avs)[tid] = ((const float4*)(g_av2 + grp*2048))[tid];

  // ---------- S phase: S[i][h] = sum_j relu(Ai+Aj+adj*w1e)*valid ----------
  float4 w14 = ((const float4*)g_w1e)[hq];
  float4 Ai4[4], acc4[4];
  #pragma unroll
  for (int r = 0; r < 4; ++r){
    Ai4[r] = *(const float4*)(projr + (n0+r)*PO + 4*hq);
    acc4[r] = make_float4(0.f, 0.f, 0.f, 0.f);
  }
  __syncthreads();
  const float* ajp = projr + (bb*NN + q*32)*PO + 256 + 4*hq;
  const float4* avp = ((const float4*)avs) + q*64;   // 2 float4 per j
  #pragma unroll 4
  for (int j = 0; j < 32; ++j){
    float4 a4 = *(const float4*)ajp; ajp += PO;
    float4 av01 = avp[2*j];
    float4 av23 = avp[2*j+1];
    float adv[4] = {av01.x, av01.z, av23.x, av23.z};
    float vmv[4] = {av01.y, av01.w, av23.y, av23.w};
    #pragma unroll
    for (int r = 0; r < 4; ++r){
      float vx = Ai4[r].x + a4.x;
      float vy = Ai4[r].y + a4.y;
      float vz = Ai4[r].z + a4.z;
      float vw = Ai4[r].w + a4.w;
      vx = fmaf(adv[r], w14.x, vx);
      vy = fmaf(adv[r], w14.y, vy);
      vz = fmaf(adv[r], w14.z, vz);
      vw = fmaf(adv[r], w14.w, vw);
      vx = fmaxf(vx, 0.f); vy = fmaxf(vy, 0.f);
      vz = fmaxf(vz, 0.f); vw = fmaxf(vw, 0.f);
      acc4[r].x = fmaf(vx, vmv[r], acc4[r].x);
      acc4[r].y = fmaf(vy, vmv[r], acc4[r].y);
      acc4[r].z = fmaf(vz, vmv[r], acc4[r].z);
      acc4[r].w = fmaf(vw, vmv[r], acc4[r].w);
    }
  }
  if (q){
    #pragma unroll
    for (int r = 0; r < 4; ++r) red[q-1][r][hq] = acc4[r];
  }
  __syncthreads();
  if (q == 0){
    #pragma unroll
    for (int r = 0; r < 4; ++r){
      float4 sv = acc4[r];
      #pragma unroll
      for (int p = 0; p < 7; ++p){
        float4 pv = red[p][r][hq];
        sv.x += pv.x; sv.y += pv.y; sv.z += pv.z; sv.w += pv.w;
      }
      ((float4*)&Ssh[r][0])[hq] = sv;
    }
  }
  __syncthreads();                     // S done; part may overwrite red

  // ---------- gi GEMM: part = Ssh @ MT (K split 4 ways, 384 threads) --------
  if (tid < 384){
    int c96 = tid % 96, sub = tid / 96;
    int k0 = sub*64;
    float4 acc[4];
    #pragma unroll
    for (int r = 0; r < 4; ++r) acc[r] = make_float4(0.f,0.f,0.f,0.f);
    const float4* MT4 = (const float4*)g_MT;   // [256][96]
    #pragma unroll 8
    for (int k = 0; k < 64; ++k){
      float4 m = MT4[(k0+k)*96 + c96];
      #pragma unroll
      for (int r = 0; r < 4; ++r){
        float sv = Ssh[r][k0+k];
        acc[r].x = fmaf(sv, m.x, acc[r].x);
        acc[r].y = fmaf(sv, m.y, acc[r].y);
        acc[r].z = fmaf(sv, m.z, acc[r].z);
        acc[r].w = fmaf(sv, m.w, acc[r].w);
      }
    }
    #pragma unroll
    for (int r = 0; r < 4; ++r) ((float4*)&part[sub][r][0])[c96] = acc[r];
  }
  __syncthreads();
  if (tid < 384){
    int g = tid;
    float bvg = g_bv[g], bihg = g_bihf[g];
    #pragma unroll
    for (int r = 0; r < 4; ++r){
      float gi = part[0][r][g] + part[1][r][g] + part[2][r][g] + part[3][r][g]
               + g_deg[n0+r]*bvg + bihg;
      float gh = projr[(n0+r)*PO + 512 + g];
      if (g < 256) Aa[r][g] = gi + gh;
      else { Aa[r][g] = gi; Bs[r][g-256] = gh; }
    }
  }
  __syncthreads();
  // ---------- GRU ----------
  if (tid < 128){
    int f = tid;
    #pragma unroll
    for (int r = 0; r < 4; ++r){
      int node = n0 + r;
      float rr = 1.f/(1.f + __expf(-Aa[r][f]));
      float zz = 1.f/(1.f + __expf(-Aa[r][128+f]));
      float hn = Bs[r][f];
      float narg = Aa[r][256+f] + rr*hn;
      float e = __expf(2.f*narg);
      float nn = 1.f - 2.f/(e + 1.f);
      float hp_ = g_h[node*FD + f];
      float hv = (1.f - zz)*nn + zz*hp_;
      hv *= g_mask[node];
      hsh[r][f] = hv;
      g_h[node*FD + f] = hv;
      if (last){
        if (isb) ((bf16*)out)[node*FD + f] = __float2bfloat16(hv);
        else     ((float*)out)[node*FD + f] = hv;
      }
    }
  }
  __syncthreads();

  if (!last){                          // proj for this step's h -> write buffer
    int c = tid & 255, fh = tid >> 8;  // f-split for parallelism
    float4 a[4];
    #pragma unroll
    for (int r = 0; r < 4; ++r) a[r] = make_float4(0.f,0.f,0.f,0.f);
    if (c < 224){
      const float4* PT4 = (const float4*)g_PT + fh*64*224 + c;
      #pragma unroll 4
      for (int f = 0; f < 64; ++f){
        float4 w = *PT4; PT4 += 224;
        #pragma unroll
        for (int r = 0; r < 4; ++r){
          float hv = hsh[r][fh*64 + f];
          a[r].x = fmaf(hv, w.x, a[r].x);
          a[r].y = fmaf(hv, w.y, a[r].y);
          a[r].z = fmaf(hv, w.z, a[r].z);
          a[r].w = fmaf(hv, w.w, a[r].w);
        }
      }
      if (fh == 1){
        #pragma unroll
        for (int r = 0; r < 4; ++r) ppart[r][c] = a[r];
      }
    }
    __syncthreads();
    if (fh == 0 && c < 224){
      float4 pbv = ((const float4*)g_pbias)[c];
      #pragma unroll
      for (int r = 0; r < 4; ++r){
        float4 p = ppart[r][c];
        float4 res;
        res.x = a[r].x + p.x + pbv.x;
        res.y = a[r].y + p.y + pbv.y;
        res.z = a[r].z + p.z + pbv.z;
        res.w = a[r].w + p.w + pbv.w;
        ((float4*)(projw + (n0+r)*PO))[c] = res;
      }
    }
  }
}

extern "C" void kernel_launch(void* const* d_in, const int* in_sizes, int n_in,
                              void* d_out, int out_size, void* d_ws, size_t ws_size,
                              hipStream_t stream){
  (void)in_sizes; (void)n_in; (void)out_size; (void)d_ws; (void)ws_size;
  const void* x    = d_in[0];
  const void* adj  = d_in[1];
  const void* mask = d_in[2];
  const void* W1   = d_in[3];
  const void* b1   = d_in[4];
  const void* W2   = d_in[5];
  const void* b2   = d_in[6];
  const void* Wih  = d_in[7];
  const void* bih  = d_in[8];
  const void* Whh  = d_in[9];
  const void* bhh  = d_in[10];

  k_init_a<<<2241, 256, 0, stream>>>(x, adj, mask, W1, b1, Wih, Whh, bhh);
  k_init_MT<<<257 + 256, 384, 0, stream>>>(W2, b2, bih, mask);   // + step-0 proj

  for (int s = 1; s <= STEPS; ++s){
    int woff = (s & 1) * NODES * PO;          // write buffer for step s
    int roff = ((s + 1) & 1) * NODES * PO;    // read buffer (step s-1's write)
    k_step<<<256, 512, 0, stream>>>(d_out, mask, s == STEPS ? 1 : 0, roff, woff);
  }
}